// Round 17
// baseline (880.693 us; speedup 1.0000x reference)
//
#include <hip/hip_runtime.h>
#include <stdint.h>

// VQ Quantizer on MI355X. T=32768 tokens, K=8192 codes, C=256, fp32 in/out.
// Round 9 (resubmit after broker timeout): 2-kernel pipeline. prep =
// cvt_data + cvt_cb fused (branch on blockIdx; emits Ap, Bp, e2, e2b, out3).
// screen = R11/R15's measured 173.2us main loop (byte-identical) +
// last-arrival-block fused rescore: after cand writes,
// threadfence+atomicAdd(ctr[bm]); the 4th block for a token group acquires
// (threadfence + volatile cand reads) and rescores its 64 tokens inline
// (R15-verified streaming rescore: x from out3, lane-uniform bestc, writes
// out1/out2). No spin -> no deadlock; rescore overlaps screen instead of
// running as a serial tail.
//   screen key u = 0.5*e2 + 256 - x.e  (Ap stores -x so acc = e2b + (-x).e)
//   u32 key = (f32bits(u) & ~63) | nt; top-2/thread, lane/wave merged.
// gll16 offset imm MUST stay 0 (R10 measured absmax=7.05 with imm!=0).

#define T_TOT 32768
#define K_TOT 8192
#define CD    256
#define SPLITS 4
#define NSPLIT 2048
#define MT    64            // tokens per screen block
#define NTI   32            // 64-code tiles per split

typedef _Float16 h8 __attribute__((ext_vector_type(8)));
typedef float f4 __attribute__((ext_vector_type(4)));
typedef unsigned long long u64;
typedef unsigned int u32;

// ---------------- ws layout ----------------
#define WS_AP    0u            // _Float16 frag-layout [2048 g][8 kk][64 l][8]  16 MB (NEGATED)
#define WS_BP    16777216u     // _Float16 frag-layout [512 g][8 kk][64 l][8]    4 MB
#define WS_E2    20971520u     // float [8192]
#define WS_E2B   21004288u     // float [8192]  (0.5*e2 + 256)
#define WS_CAND  21037056u     // u64 [32768][4][2]        2 MB
#define WS_CTR   23134208u     // int [512] last-arrival counters
#define WS_NEED  23265280u

__device__ __forceinline__ u64 shfl_xor_u64(u64 v, int off, int w) {
  unsigned lo = (unsigned)v, hi = (unsigned)(v >> 32);
  lo = __shfl_xor(lo, off, w);
  hi = __shfl_xor(hi, off, w);
  return ((u64)hi << 32) | lo;
}
__device__ __forceinline__ u64 umin64(u64 a, u64 b) { return a < b ? a : b; }
__device__ __forceinline__ u64 umax64(u64 a, u64 b) { return a < b ? b : a; }
__device__ __forceinline__ u32 umin32(u32 a, u32 b) { return a < b ? a : b; }
__device__ __forceinline__ u32 umax32(u32 a, u32 b) { return a < b ? b : a; }

__device__ __forceinline__ void gll16(const void* g, void* l) {
  __builtin_amdgcn_global_load_lds(
      (const __attribute__((address_space(1))) void*)g,
      (__attribute__((address_space(3))) void*)l, 16, 0, 0);
}

// stage one 16-code fragment group (8 kk x 64 lanes x 16B = 8KB), per-wave.
__device__ __forceinline__ void stage_b(const _Float16* __restrict__ gsrc,
                                        _Float16* ldst, int lane) {
  #pragma unroll
  for (int kk = 0; kk < 8; ++kk)
    gll16(gsrc + kk * 512 + lane * 8, ldst + kk * 512);
}

// data[t,c] = in[(t>>10)*262144 + c*1024 + (t&1023)]  (NCHW -> [T,C])

// ============ main path ============

// fused prep: blocks 0..1023 = cvt_data (Ap NEGATED fp16 + out3 fp32 rows);
// blocks 1024..1535 = cvt_cb (Bp frag fp16, e2 exact, e2b = 0.5*e2+256).
__global__ __launch_bounds__(256) void prep_kernel(
    const float* __restrict__ in, const float* __restrict__ cb,
    _Float16* __restrict__ Ap, _Float16* __restrict__ Bp,
    float* __restrict__ e2, float* __restrict__ e2b,
    float* __restrict__ out3) {
  __shared__ float S[32][257];
  const int tid = threadIdx.x;
  if (blockIdx.x < 1024) {
    const int t0 = blockIdx.x * 32;
    const int nbase = (t0 >> 10) << 18;
    const int tin = t0 & 1023;
    // float4 staging: 2048 quads (tt-fast), 8/thread; tin%32==0 -> aligned
    #pragma unroll
    for (int p = 0; p < 8; ++p) {
      const int id = p * 256 + tid;
      const int cc = id >> 3, t4 = (id & 7) * 4;
      const float4 v = *(const float4*)(in + nbase + cc * 1024 + tin + t4);
      S[t4 + 0][cc] = v.x;
      S[t4 + 1][cc] = v.y;
      S[t4 + 2][cc] = v.z;
      S[t4 + 3][cc] = v.w;
    }
    __syncthreads();
    const u64 g0 = (u64)(t0 >> 4);
    #pragma unroll
    for (int p = 0; p < 4; ++p) {
      const int id = p * 256 + tid;
      const int gl = id >> 9, kk = (id >> 6) & 7, l = id & 63;
      const int row = gl * 16 + (l & 15);
      const int c0 = kk * 32 + (l >> 4) * 8;
      h8 hv;
      #pragma unroll
      for (int j = 0; j < 8; ++j) hv[j] = (_Float16)(-S[row][c0 + j]);
      *(h8*)(Ap + ((g0 + (u64)gl) * 8 + kk) * 512 + (u64)l * 8) = hv;
    }
    #pragma unroll 8
    for (int tt = 0; tt < 32; ++tt)
      out3[(u64)(t0 + tt) * CD + tid] = S[tt][tid];
  } else {
    const int g = blockIdx.x - 1024;       // 0..511
    float (*Cs)[260] = (float(*)[260])&S[0][0];  // 16*260 floats fits in S
    #pragma unroll
    for (int r = 0; r < 16; ++r)
      Cs[r][tid] = cb[((u64)g * 16 + r) * 256 + tid];
    __syncthreads();
    const int w = tid >> 6, lane = tid & 63;
    #pragma unroll
    for (int rr = 0; rr < 4; ++rr) {
      const int row = w * 4 + rr;
      const float4 v = *(const float4*)&Cs[row][lane * 4];
      float s = v.x * v.x + v.y * v.y + v.z * v.z + v.w * v.w;
      #pragma unroll
      for (int off = 32; off >= 1; off >>= 1) s += __shfl_xor(s, off, 64);
      if (lane == 0) {
        e2[g * 16 + row] = s;
        e2b[g * 16 + row] = 0.5f * s + 256.0f;
      }
    }
    #pragma unroll
    for (int p = 0; p < 2; ++p) {
      const int id = p * 256 + tid;
      const int kk = id >> 6, l = id & 63;
      const int row = l & 15, c0 = kk * 32 + (l >> 4) * 8;
      h8 hv;
      #pragma unroll
      for (int j = 0; j < 8; ++j) hv[j] = (_Float16)Cs[row][c0 + j];
      *(h8*)(Bp + ((u64)g * 8 + kk) * 512 + (u64)l * 8) = hv;
    }
  }
}

// hybrid MFMA screen (main loop byte-identical to R11/R15 measured kernel)
// + last-arrival-block fused rescore for the bm's 64 tokens.
__global__ __launch_bounds__(256, 2) void screen_kernel(
    const _Float16* __restrict__ Ap, const _Float16* __restrict__ Bp,
    const float* __restrict__ cbf, const float* __restrict__ e2b,
    const float* __restrict__ e2x, u64* __restrict__ cand,
    int* __restrict__ ctr, float* outp) {
  __shared__ __align__(16) _Float16 bsm[4][2][4096];   // 64 KB: per-wave 2x8KB
  __shared__ __align__(16) float e2s[2048];            // 8 KB e2b slice
  __shared__ int lastf;

  const int tid = threadIdx.x;
  const int lane = tid & 63;
  const int w = __builtin_amdgcn_readfirstlane(tid >> 6);  // wave-uniform SGPR
  const int q = lane >> 4;
  const int c15 = lane & 15;

  const int x = blockIdx.x & 7;
  const int m = blockIdx.x >> 3;     // 0..255
  const int split = x >> 1;
  const int bm = m * 2 + (x & 1);    // 0..511
  const int t0 = bm * MT;
  const int n0s = split * NSPLIT;

  // ---- prologue: A frags -> regs; B slots 0/1; e2 table; one barrier ----
  const h8* ap = (const h8*)Ap + (u64)(t0 >> 4) * 512 + lane;
  h8 af[4][8];
  #pragma unroll
  for (int mi = 0; mi < 4; ++mi)
    #pragma unroll
    for (int kk = 0; kk < 8; ++kk)
      af[mi][kk] = ap[(mi * 8 + kk) * 64];

  const _Float16* bg = Bp + ((u64)(n0s >> 4) + (u64)w) * 4096;   // uniform
  stage_b(bg, &bsm[w][0][0], lane);            // nt=0
  stage_b(bg + 16384, &bsm[w][1][0], lane);    // nt=1
  gll16(e2b + n0s + w * 512 + lane * 4, e2s + w * 512);
  gll16(e2b + n0s + w * 512 + 256 + lane * 4, e2s + w * 512 + 256);

  u32 m1[16], m2[16];
  #pragma unroll
  for (int r = 0; r < 16; ++r) { m1[r] = 0xffffffffu; m2[r] = 0xffffffffu; }

  __syncthreads();    // drains all prologue loads

  #pragma unroll 2
  for (int nt = 0; nt < NTI; ++nt) {
    asm volatile("s_waitcnt vmcnt(8)" ::: "memory");
    _Float16* slot = &bsm[w][nt & 1][0];
    const float ev = e2s[nt * 64 + w * 16 + c15];
    h8 bf[8];
    #pragma unroll
    for (int kk = 0; kk < 8; ++kk)
      bf[kk] = *(const h8*)(slot + kk * 512 + lane * 8);

    f4 acc[4];
    #pragma unroll
    for (int mi = 0; mi < 4; ++mi) acc[mi] = (f4){ev, ev, ev, ev};
    __builtin_amdgcn_s_setprio(1);
    #pragma unroll
    for (int kk = 0; kk < 8; ++kk) {
      acc[0] = __builtin_amdgcn_mfma_f32_16x16x32_f16(af[0][kk], bf[kk], acc[0], 0, 0, 0);
      acc[1] = __builtin_amdgcn_mfma_f32_16x16x32_f16(af[1][kk], bf[kk], acc[1], 0, 0, 0);
      acc[2] = __builtin_amdgcn_mfma_f32_16x16x32_f16(af[2][kk], bf[kk], acc[2], 0, 0, 0);
      acc[3] = __builtin_amdgcn_mfma_f32_16x16x32_f16(af[3][kk], bf[kk], acc[3], 0, 0, 0);
    }
    __builtin_amdgcn_s_setprio(0);

    asm volatile("s_waitcnt lgkmcnt(0)" ::: "memory");   // ds_reads retired
    __builtin_amdgcn_sched_barrier(0);                   // no gll16 hoist
    const int g2 = (nt + 2 < NTI) ? nt + 2 : NTI - 1;
    stage_b(bg + (u64)g2 * 16384, slot, lane);

    #pragma unroll
    for (int mi = 0; mi < 4; ++mi)
      #pragma unroll
      for (int reg = 0; reg < 4; ++reg) {
        const int r = mi * 4 + reg;
        const u32 k = (__float_as_uint(acc[mi][reg]) & ~63u) | (u32)nt;
        const u32 hi = umax32(m1[r], k);
        m1[r] = umin32(m1[r], k);
        m2[r] = umin32(m2[r], hi);
      }
  }

  // ---- merge across the 16 c15 lanes (per q group), rows = tokens ----
  u64 P1[16], P2[16];
  #pragma unroll
  for (int r = 0; r < 16; ++r) {
    const u32 l1 = m1[r] & 63u, l2 = m2[r] & 63u;
    const u32 col1 = (u32)(n0s + (int)l1 * 64 + w * 16 + c15);
    const u32 col2 = (u32)(n0s + (int)l2 * 64 + w * 16 + c15);
    P1[r] = ((u64)m1[r] << 32) | col1;
    P2[r] = ((u64)m2[r] << 32) | col2;
  }
  #pragma unroll
  for (int st = 1; st < 16; st <<= 1) {
    #pragma unroll
    for (int r = 0; r < 16; ++r) {
      const u64 o1 = shfl_xor_u64(P1[r], st, 16);
      const u64 o2 = shfl_xor_u64(P2[r], st, 16);
      const u64 n1 = umin64(P1[r], o1);
      const u64 hi = umax64(P1[r], o1);
      P2[r] = umin64(hi, umin64(P2[r], o2));
      P1[r] = n1;
    }
  }
  __syncthreads();                   // all waves done reading their B slots
  u64* mb = (u64*)&bsm[0][0][0];     // reuse LDS: [4 w][64 rows][2]
  if (c15 == 0) {
    #pragma unroll
    for (int r = 0; r < 16; ++r) {
      const int mi = r >> 2, reg = r & 3;
      const int row = mi * 16 + q * 4 + reg;
      mb[(w * 64 + row) * 2 + 0] = P1[r];
      mb[(w * 64 + row) * 2 + 1] = P2[r];
    }
  }
  __syncthreads();
  if (tid < 64) {
    const u64 a1 = mb[(0 * 64 + tid) * 2], a2 = mb[(0 * 64 + tid) * 2 + 1];
    const u64 b1 = mb[(1 * 64 + tid) * 2], b2 = mb[(1 * 64 + tid) * 2 + 1];
    const u64 c1 = mb[(2 * 64 + tid) * 2], c2 = mb[(2 * 64 + tid) * 2 + 1];
    const u64 d1 = mb[(3 * 64 + tid) * 2], d2 = mb[(3 * 64 + tid) * 2 + 1];
    const u64 x1 = umin64(a1, b1);
    const u64 x2 = umin64(umax64(a1, b1), umin64(a2, b2));
    const u64 y1 = umin64(c1, d1);
    const u64 y2 = umin64(umax64(c1, d1), umin64(c2, d2));
    const u64 n1 = umin64(x1, y1);
    const u64 n2 = umin64(umax64(x1, y1), umin64(x2, y2));
    cand[(u64)(t0 + tid) * 8 + split * 2 + 0] = n1;
    cand[(u64)(t0 + tid) * 8 + split * 2 + 1] = n2;
  }

  // ---- last-arrival-block fused rescore (threadFenceReduction pattern) ----
  __threadfence();                   // release: flush cand writes (all lanes)
  __syncthreads();
  if (tid == 0) lastf = (atomicAdd(ctr + bm, 1) == SPLITS - 1) ? 1 : 0;
  __syncthreads();
  if (!lastf) return;
  __threadfence();                   // acquire: no stale cand via L1

  float* out1 = outp;
  float* out2 = outp + 8388608;
  const float* x3 = outp + 16777216;
  #pragma unroll 1
  for (int s = 0; s < 16; ++s) {
    const int t = t0 + w * 16 + s;
    int colv = 0;
    if (lane < 8)
      colv = (int)(u32)*((volatile const u64*)cand + (u64)t * 8 + lane);
    const float4 xv = *(const float4*)(x3 + (u64)t * CD + lane * 4);
    float bestd = 1e30f; int bestc = 0x7fffffff;
    #pragma unroll
    for (int j = 0; j < 8; ++j) {
      const int col = __shfl(colv, j, 64);
      const float4 e = *(const float4*)(cbf + (u64)col * CD + lane * 4);
      float p4 = xv.x * e.x + xv.y * e.y + xv.z * e.z + xv.w * e.w;
      #pragma unroll
      for (int off = 32; off >= 1; off >>= 1) p4 += __shfl_xor(p4, off, 64);
      const float d = e2x[col] - 2.0f * p4;
      if (d < bestd || (d == bestd && col < bestc)) { bestd = d; bestc = col; }
    }
    const float4 q4 = *(const float4*)(cbf + (u64)bestc * CD + lane * 4);
    float4 qd4;
    qd4.x = xv.x + (q4.x - xv.x);
    qd4.y = xv.y + (q4.y - xv.y);
    qd4.z = xv.z + (q4.z - xv.z);
    qd4.w = xv.w + (q4.w - xv.w);
    const u64 o = (u64)t * CD + lane * 4;
    *(float4*)(out1 + o) = q4;
    *(float4*)(out2 + o) = qd4;
  }
}

// ============ fallback path (exact fp32), used if ws too small ============

__global__ __launch_bounds__(256) void norms_kernel(const float* __restrict__ in,
                                                    const float* __restrict__ cb,
                                                    float* __restrict__ e2,
                                                    float* __restrict__ x2) {
  const int b = blockIdx.x;
  const int tid = threadIdx.x;
  if (b < 2048) {
    const int wave = tid >> 6, lane = tid & 63;
    const int row = b * 4 + wave;
    const float4 v = *(const float4*)(cb + row * CD + lane * 4);
    float s = v.x * v.x + v.y * v.y + v.z * v.z + v.w * v.w;
    #pragma unroll
    for (int off = 32; off >= 1; off >>= 1) s += __shfl_down(s, off, 64);
    if (lane == 0) e2[row] = s;
  } else {
    const int t = (b - 2048) * 256 + tid;
    const float* p = in + ((t >> 10) << 18) + (t & 1023);
    float s = 0.f;
    #pragma unroll 8
    for (int c = 0; c < CD; ++c) { const float v = p[c << 10]; s += v * v; }
    x2[t] = s;
  }
}

__global__ __launch_bounds__(256) void dist_argmin_kernel(
    const float* __restrict__ in, const float* __restrict__ cb,
    const float* __restrict__ e2, const float* __restrict__ x2,
    u64* __restrict__ packed) {
  __shared__ __align__(16) float As_[32][128];
  __shared__ __align__(16) float Bs_[32][128];
  const int tid = threadIdx.x;
  const int tx = tid & 15, ty = tid >> 4;
  const int tb = blockIdx.x & 255;
  const int ks = blockIdx.x >> 8;
  const int t0 = tb * 128;
  const int nbase = (t0 >> 10) << 18;
  const int tin = t0 & 1023;
  float xi[8];
  #pragma unroll
  for (int i = 0; i < 8; ++i)
    xi[i] = x2[t0 + ty * 4 + (i & 3) + ((i >> 2) << 6)];
  u64 best[8];
  #pragma unroll
  for (int i = 0; i < 8; ++i) best[i] = ~0ull;
  for (int kt = 0; kt < 32; ++kt) {
    const int k0 = ks * 4096 + kt * 128;
    float acc[8][8];
    #pragma unroll
    for (int i = 0; i < 8; ++i)
      #pragma unroll
      for (int j = 0; j < 8; ++j) acc[i][j] = 0.f;
    float ej[8];
    #pragma unroll
    for (int j = 0; j < 8; ++j)
      ej[j] = e2[k0 + tx * 4 + (j & 3) + ((j >> 2) << 6)];
    for (int ch = 0; ch < 8; ++ch) {
      const int c0 = ch * 32;
      #pragma unroll
      for (int p = 0; p < 4; ++p) {
        const int l = p * 1024 + tid * 4;
        const int cc = l >> 7, tt = l & 127;
        *(float4*)&As_[cc][tt] =
            *(const float4*)(in + nbase + (c0 + cc) * 1024 + tin + tt);
      }
      #pragma unroll
      for (int p = 0; p < 4; ++p) {
        const int ix = p * 256 + tid;
        const int kk = ix >> 3, cs = (ix & 7) * 4;
        const float4 v = *(const float4*)(cb + (k0 + kk) * CD + c0 + cs);
        Bs_[cs + 0][kk] = v.x; Bs_[cs + 1][kk] = v.y;
        Bs_[cs + 2][kk] = v.z; Bs_[cs + 3][kk] = v.w;
      }
      __syncthreads();
      #pragma unroll
      for (int cc = 0; cc < 32; ++cc) {
        const float4 a0 = *(const float4*)&As_[cc][ty * 4];
        const float4 a1 = *(const float4*)&As_[cc][64 + ty * 4];
        const float4 b0 = *(const float4*)&Bs_[cc][tx * 4];
        const float4 b1 = *(const float4*)&Bs_[cc][64 + tx * 4];
        const float a[8]  = {a0.x, a0.y, a0.z, a0.w, a1.x, a1.y, a1.z, a1.w};
        const float bb[8] = {b0.x, b0.y, b0.z, b0.w, b1.x, b1.y, b1.z, b1.w};
        #pragma unroll
        for (int i = 0; i < 8; ++i)
          #pragma unroll
          for (int j = 0; j < 8; ++j)
            acc[i][j] += a[i] * bb[j];
      }
      __syncthreads();
    }
    #pragma unroll
    for (int i = 0; i < 8; ++i) {
      u64 m = best[i];
      #pragma unroll
      for (int j = 0; j < 8; ++j) {
        const float dist = (xi[i] - 2.0f * acc[i][j]) + ej[j];
        const int kidx = k0 + tx * 4 + (j & 3) + ((j >> 2) << 6);
        const u64 pk = ((u64)__float_as_uint(dist) << 32) | (unsigned)kidx;
        m = pk < m ? pk : m;
      }
      best[i] = m;
    }
  }
  #pragma unroll
  for (int i = 0; i < 8; ++i) {
    u64 m = best[i];
    #pragma unroll
    for (int off = 8; off >= 1; off >>= 1) {
      const u64 o = shfl_xor_u64(m, off, 16);
      m = o < m ? o : m;
    }
    if (tx == 0)
      atomicMin(&packed[t0 + ty * 4 + (i & 3) + ((i >> 2) << 6)], m);
  }
}

__global__ __launch_bounds__(256) void output_kernel(
    const float* __restrict__ in, const float* __restrict__ cb,
    const u64* __restrict__ packed, float* __restrict__ out) {
  __shared__ float Ds[32][257];
  __shared__ int idxs[32];
  const int tid = threadIdx.x;
  const int t0 = blockIdx.x * 32;
  const int nbase = (t0 >> 10) << 18;
  const int tin = t0 & 1023;
  if (tid < 32) idxs[tid] = (int)(packed[t0 + tid] & 0xffffffffull);
  #pragma unroll 8
  for (int p = 0; p < 32; ++p) {
    const int lin = p * 256 + tid;
    const int cc = lin >> 5, tt = lin & 31;
    Ds[tt][cc] = in[nbase + cc * 1024 + tin + tt];
  }
  __syncthreads();
  float* out1 = out;
  float* out2 = out + 8388608;
  float* out3 = out + 16777216;
  for (int tt = 0; tt < 32; ++tt) {
    const float d = Ds[tt][tid];
    const int k = idxs[tt];
    const float q = cb[k * CD + tid];
    const float qd = d + (q - d);
    const int o = (t0 + tt) * CD + tid;
    out1[o] = q;
    out2[o] = qd;
    out3[o] = d;
  }
}

extern "C" void kernel_launch(void* const* d_in, const int* in_sizes, int n_in,
                              void* d_out, int out_size, void* d_ws, size_t ws_size,
                              hipStream_t stream) {
  const float* in = (const float*)d_in[0];
  const float* cb = (const float*)d_in[1];
  float* out = (float*)d_out;

  if (ws_size >= WS_NEED) {
    _Float16* Ap = (_Float16*)((char*)d_ws + WS_AP);
    _Float16* Bp = (_Float16*)((char*)d_ws + WS_BP);
    float* e2  = (float*)((char*)d_ws + WS_E2);
    float* e2b = (float*)((char*)d_ws + WS_E2B);
    u64* cand  = (u64*)((char*)d_ws + WS_CAND);
    int* ctr   = (int*)((char*)d_ws + WS_CTR);
    float* out3 = out + 16777216;

    (void)hipMemsetAsync(ctr, 0, 512 * sizeof(int), stream);
    prep_kernel<<<1536, 256, 0, stream>>>(in, cb, Ap, Bp, e2, e2b, out3);
    screen_kernel<<<(T_TOT / MT) * SPLITS, 256, 0, stream>>>(
        Ap, Bp, cb, e2b, e2, cand, ctr, out);
  } else {
    u64* packed = (u64*)d_ws;
    float* e2 = (float*)((char*)d_ws + 262144);
    float* x2 = (float*)((char*)d_ws + 294912);
    (void)hipMemsetAsync(packed, 0xFF, T_TOT * sizeof(u64), stream);
    norms_kernel<<<2176, 256, 0, stream>>>(in, cb, e2, x2);
    dist_argmin_kernel<<<512, 256, 0, stream>>>(in, cb, e2, x2, packed);
    output_kernel<<<T_TOT / 32, 256, 0, stream>>>(in, cb, packed, out);
  }
}

// Round 19
// 327.365 us; speedup vs baseline: 2.6902x; 2.6902x over previous
//
#include <hip/hip_runtime.h>
#include <stdint.h>

// VQ Quantizer on MI355X. T=32768 tokens, K=8192 codes, C=256, fp32 in/out.
// Round 10 (resubmit after broker timeout): revert R17's fence-fused rescore
// (measured 880us: per-block __threadfence L2-writeback x2048 evicted the
// L2-resident Bp -> MfmaUtil 6.8%, FETCH 37->96MB). Back to R15's
// measured-best screen+rescore (329.7us, absmax 0), keeping only the
// fence-free prep fusion from R16: prep = cvt_data + cvt_cb in ONE dispatch
// (independent blocks, no fences; ran correctly inside R17). 3 dispatches.
//   screen key u = 0.5*e2 + 256 - x.e  (Ap stores -x so acc = e2b + (-x).e)
//   u32 key = (f32bits(u) & ~63) | nt; top-2/thread, lane/wave merged;
//   exact fp32 streaming rescore of 8 candidates (reads out3, writes
//   out1/out2, lane-uniform bestc).
// gll16 offset imm MUST stay 0 (R10 measured absmax=7.05 with imm!=0).

#define T_TOT 32768
#define K_TOT 8192
#define CD    256
#define SPLITS 4
#define NSPLIT 2048
#define MT    64            // tokens per screen block
#define NTI   32            // 64-code tiles per split

typedef _Float16 h8 __attribute__((ext_vector_type(8)));
typedef float f4 __attribute__((ext_vector_type(4)));
typedef unsigned long long u64;
typedef unsigned int u32;

// ---------------- ws layout ----------------
#define WS_AP    0u            // _Float16 frag-layout [2048 g][8 kk][64 l][8]  16 MB (NEGATED)
#define WS_BP    16777216u     // _Float16 frag-layout [512 g][8 kk][64 l][8]    4 MB
#define WS_E2    20971520u     // float [8192]
#define WS_E2B   21004288u     // float [8192]  (0.5*e2 + 256)
#define WS_CAND  21037056u     // u64 [32768][4][2]        2 MB
#define WS_NEED  23265280u

__device__ __forceinline__ u64 shfl_xor_u64(u64 v, int off, int w) {
  unsigned lo = (unsigned)v, hi = (unsigned)(v >> 32);
  lo = __shfl_xor(lo, off, w);
  hi = __shfl_xor(hi, off, w);
  return ((u64)hi << 32) | lo;
}
__device__ __forceinline__ u64 umin64(u64 a, u64 b) { return a < b ? a : b; }
__device__ __forceinline__ u64 umax64(u64 a, u64 b) { return a < b ? b : a; }
__device__ __forceinline__ u32 umin32(u32 a, u32 b) { return a < b ? a : b; }
__device__ __forceinline__ u32 umax32(u32 a, u32 b) { return a < b ? b : a; }

__device__ __forceinline__ void gll16(const void* g, void* l) {
  __builtin_amdgcn_global_load_lds(
      (const __attribute__((address_space(1))) void*)g,
      (__attribute__((address_space(3))) void*)l, 16, 0, 0);
}

// stage one 16-code fragment group (8 kk x 64 lanes x 16B = 8KB), per-wave.
__device__ __forceinline__ void stage_b(const _Float16* __restrict__ gsrc,
                                        _Float16* ldst, int lane) {
  #pragma unroll
  for (int kk = 0; kk < 8; ++kk)
    gll16(gsrc + kk * 512 + lane * 8, ldst + kk * 512);
}

// data[t,c] = in[(t>>10)*262144 + c*1024 + (t&1023)]  (NCHW -> [T,C])

// ============ main path ============

// fused prep: blocks 0..1023 = cvt_data (Ap NEGATED fp16 + out3 fp32 rows);
// blocks 1024..1535 = cvt_cb (Bp frag fp16, e2 exact, e2b = 0.5*e2+256).
// Independent blocks, no fences.
__global__ __launch_bounds__(256) void prep_kernel(
    const float* __restrict__ in, const float* __restrict__ cb,
    _Float16* __restrict__ Ap, _Float16* __restrict__ Bp,
    float* __restrict__ e2, float* __restrict__ e2b,
    float* __restrict__ out3) {
  __shared__ float S[32][257];
  const int tid = threadIdx.x;
  if (blockIdx.x < 1024) {
    const int t0 = blockIdx.x * 32;
    const int nbase = (t0 >> 10) << 18;
    const int tin = t0 & 1023;
    // float4 staging: 2048 quads (tt-fast), 8/thread; tin%32==0 -> aligned
    #pragma unroll
    for (int p = 0; p < 8; ++p) {
      const int id = p * 256 + tid;
      const int cc = id >> 3, t4 = (id & 7) * 4;
      const float4 v = *(const float4*)(in + nbase + cc * 1024 + tin + t4);
      S[t4 + 0][cc] = v.x;
      S[t4 + 1][cc] = v.y;
      S[t4 + 2][cc] = v.z;
      S[t4 + 3][cc] = v.w;
    }
    __syncthreads();
    const u64 g0 = (u64)(t0 >> 4);
    #pragma unroll
    for (int p = 0; p < 4; ++p) {
      const int id = p * 256 + tid;
      const int gl = id >> 9, kk = (id >> 6) & 7, l = id & 63;
      const int row = gl * 16 + (l & 15);
      const int c0 = kk * 32 + (l >> 4) * 8;
      h8 hv;
      #pragma unroll
      for (int j = 0; j < 8; ++j) hv[j] = (_Float16)(-S[row][c0 + j]);
      *(h8*)(Ap + ((g0 + (u64)gl) * 8 + kk) * 512 + (u64)l * 8) = hv;
    }
    #pragma unroll 8
    for (int tt = 0; tt < 32; ++tt)
      out3[(u64)(t0 + tt) * CD + tid] = S[tt][tid];
  } else {
    const int g = blockIdx.x - 1024;       // 0..511
    float (*Cs)[260] = (float(*)[260])&S[0][0];  // 16*260 floats fits in S
    #pragma unroll
    for (int r = 0; r < 16; ++r)
      Cs[r][tid] = cb[((u64)g * 16 + r) * 256 + tid];
    __syncthreads();
    const int w = tid >> 6, lane = tid & 63;
    #pragma unroll
    for (int rr = 0; rr < 4; ++rr) {
      const int row = w * 4 + rr;
      const float4 v = *(const float4*)&Cs[row][lane * 4];
      float s = v.x * v.x + v.y * v.y + v.z * v.z + v.w * v.w;
      #pragma unroll
      for (int off = 32; off >= 1; off >>= 1) s += __shfl_xor(s, off, 64);
      if (lane == 0) {
        e2[g * 16 + row] = s;
        e2b[g * 16 + row] = 0.5f * s + 256.0f;
      }
    }
    #pragma unroll
    for (int p = 0; p < 2; ++p) {
      const int id = p * 256 + tid;
      const int kk = id >> 6, l = id & 63;
      const int row = l & 15, c0 = kk * 32 + (l >> 4) * 8;
      h8 hv;
      #pragma unroll
      for (int j = 0; j < 8; ++j) hv[j] = (_Float16)Cs[row][c0 + j];
      *(h8*)(Bp + ((u64)g * 8 + kk) * 512 + (u64)l * 8) = hv;
    }
  }
}

// hybrid MFMA screen: 64 tokens x 2048 codes per block -> top-2 per split.
// Wave w owns codes [nt*64 + w*16, +16) for all 64 tokens.
// BYTE-IDENTICAL to R11/R15's measured kernel (173.2-173.5us, absmax 0).
__global__ __launch_bounds__(256, 2) void screen_kernel(
    const _Float16* __restrict__ Ap, const _Float16* __restrict__ Bp,
    const float* __restrict__ e2b, u64* __restrict__ cand) {
  __shared__ __align__(16) _Float16 bsm[4][2][4096];   // 64 KB: per-wave 2x8KB
  __shared__ __align__(16) float e2s[2048];            // 8 KB e2b slice

  const int tid = threadIdx.x;
  const int lane = tid & 63;
  const int w = __builtin_amdgcn_readfirstlane(tid >> 6);  // wave-uniform SGPR
  const int q = lane >> 4;
  const int c15 = lane & 15;

  const int x = blockIdx.x & 7;
  const int m = blockIdx.x >> 3;     // 0..255
  const int split = x >> 1;
  const int bm = m * 2 + (x & 1);    // 0..511
  const int t0 = bm * MT;
  const int n0s = split * NSPLIT;

  // ---- prologue: A frags -> regs; B slots 0/1; e2 table; one barrier ----
  const h8* ap = (const h8*)Ap + (u64)(t0 >> 4) * 512 + lane;
  h8 af[4][8];
  #pragma unroll
  for (int mi = 0; mi < 4; ++mi)
    #pragma unroll
    for (int kk = 0; kk < 8; ++kk)
      af[mi][kk] = ap[(mi * 8 + kk) * 64];

  const _Float16* bg = Bp + ((u64)(n0s >> 4) + (u64)w) * 4096;   // uniform
  stage_b(bg, &bsm[w][0][0], lane);            // nt=0
  stage_b(bg + 16384, &bsm[w][1][0], lane);    // nt=1
  gll16(e2b + n0s + w * 512 + lane * 4, e2s + w * 512);
  gll16(e2b + n0s + w * 512 + 256 + lane * 4, e2s + w * 512 + 256);

  u32 m1[16], m2[16];
  #pragma unroll
  for (int r = 0; r < 16; ++r) { m1[r] = 0xffffffffu; m2[r] = 0xffffffffu; }

  __syncthreads();    // drains all prologue loads; only barrier before epilogue

  #pragma unroll 2
  for (int nt = 0; nt < NTI; ++nt) {
    // wait: our slot's 8 gll16 landed; the other slot's 8 may stay in flight
    asm volatile("s_waitcnt vmcnt(8)" ::: "memory");
    _Float16* slot = &bsm[w][nt & 1][0];
    const float ev = e2s[nt * 64 + w * 16 + c15];
    h8 bf[8];
    #pragma unroll
    for (int kk = 0; kk < 8; ++kk)
      bf[kk] = *(const h8*)(slot + kk * 512 + lane * 8);

    f4 acc[4];
    #pragma unroll
    for (int mi = 0; mi < 4; ++mi) acc[mi] = (f4){ev, ev, ev, ev};
    __builtin_amdgcn_s_setprio(1);
    #pragma unroll
    for (int kk = 0; kk < 8; ++kk) {
      acc[0] = __builtin_amdgcn_mfma_f32_16x16x32_f16(af[0][kk], bf[kk], acc[0], 0, 0, 0);
      acc[1] = __builtin_amdgcn_mfma_f32_16x16x32_f16(af[1][kk], bf[kk], acc[1], 0, 0, 0);
      acc[2] = __builtin_amdgcn_mfma_f32_16x16x32_f16(af[2][kk], bf[kk], acc[2], 0, 0, 0);
      acc[3] = __builtin_amdgcn_mfma_f32_16x16x32_f16(af[3][kk], bf[kk], acc[3], 0, 0, 0);
    }
    __builtin_amdgcn_s_setprio(0);

    asm volatile("s_waitcnt lgkmcnt(0)" ::: "memory");   // ds_reads retired
    __builtin_amdgcn_sched_barrier(0);                   // no gll16 hoist
    const int g2 = (nt + 2 < NTI) ? nt + 2 : NTI - 1;
    stage_b(bg + (u64)g2 * 16384, slot, lane);

    // top-2 insert: 16 token rows, 1 code (c15) per nt
    #pragma unroll
    for (int mi = 0; mi < 4; ++mi)
      #pragma unroll
      for (int reg = 0; reg < 4; ++reg) {
        const int r = mi * 4 + reg;
        const u32 k = (__float_as_uint(acc[mi][reg]) & ~63u) | (u32)nt;
        const u32 hi = umax32(m1[r], k);
        m1[r] = umin32(m1[r], k);
        m2[r] = umin32(m2[r], hi);
      }
  }

  // ---- merge across the 16 c15 lanes (per q group), rows = tokens ----
  u64 P1[16], P2[16];
  #pragma unroll
  for (int r = 0; r < 16; ++r) {
    const u32 l1 = m1[r] & 63u, l2 = m2[r] & 63u;
    const u32 col1 = (u32)(n0s + (int)l1 * 64 + w * 16 + c15);
    const u32 col2 = (u32)(n0s + (int)l2 * 64 + w * 16 + c15);
    P1[r] = ((u64)m1[r] << 32) | col1;
    P2[r] = ((u64)m2[r] << 32) | col2;
  }
  #pragma unroll
  for (int st = 1; st < 16; st <<= 1) {
    #pragma unroll
    for (int r = 0; r < 16; ++r) {
      const u64 o1 = shfl_xor_u64(P1[r], st, 16);
      const u64 o2 = shfl_xor_u64(P2[r], st, 16);
      const u64 n1 = umin64(P1[r], o1);
      const u64 hi = umax64(P1[r], o1);
      P2[r] = umin64(hi, umin64(P2[r], o2));
      P1[r] = n1;
    }
  }
  __syncthreads();                   // all waves done reading their B slots
  u64* mb = (u64*)&bsm[0][0][0];     // reuse LDS: [4 w][64 rows][2]
  if (c15 == 0) {
    #pragma unroll
    for (int r = 0; r < 16; ++r) {
      const int mi = r >> 2, reg = r & 3;
      const int row = mi * 16 + q * 4 + reg;
      mb[(w * 64 + row) * 2 + 0] = P1[r];
      mb[(w * 64 + row) * 2 + 1] = P2[r];
    }
  }
  __syncthreads();
  // ---- cross-wave merge (waves hold disjoint codes) ----
  if (tid < 64) {
    const u64 a1 = mb[(0 * 64 + tid) * 2], a2 = mb[(0 * 64 + tid) * 2 + 1];
    const u64 b1 = mb[(1 * 64 + tid) * 2], b2 = mb[(1 * 64 + tid) * 2 + 1];
    const u64 c1 = mb[(2 * 64 + tid) * 2], c2 = mb[(2 * 64 + tid) * 2 + 1];
    const u64 d1 = mb[(3 * 64 + tid) * 2], d2 = mb[(3 * 64 + tid) * 2 + 1];
    const u64 x1 = umin64(a1, b1);
    const u64 x2 = umin64(umax64(a1, b1), umin64(a2, b2));
    const u64 y1 = umin64(c1, d1);
    const u64 y2 = umin64(umax64(c1, d1), umin64(c2, d2));
    const u64 n1 = umin64(x1, y1);
    const u64 n2 = umin64(umax64(x1, y1), umin64(x2, y2));
    cand[(u64)(t0 + tid) * 8 + split * 2 + 0] = n1;
    cand[(u64)(t0 + tid) * 8 + split * 2 + 1] = n2;
  }
}

// exact fp32 rescore of 8 candidates, streaming from out3 (no LDS/barriers).
// All lanes hold bitwise-identical reduced p4 (xor-butterfly of commutative
// IEEE adds) -> bestc is lane-uniform -> gather + store per-lane directly.
// BYTE-IDENTICAL to R15's measured kernel (absmax 0).
__global__ __launch_bounds__(256) void rescore_output_kernel(
    const float* __restrict__ cb, const float* __restrict__ e2,
    const u64* __restrict__ cand, float* __restrict__ out) {
  const int tid = threadIdx.x;
  const int w = tid >> 6, lane = tid & 63;
  const int t0 = blockIdx.x * 32 + w * 8;
  float* out1 = out;
  float* out2 = out + 8388608;
  const float* out3 = out + 16777216;
  #pragma unroll 1
  for (int s = 0; s < 8; ++s) {
    const int t = t0 + s;
    int colv = 0;
    if (lane < 8) colv = (int)(u32)cand[(u64)t * 8 + lane];
    const float4 x = *(const float4*)(out3 + (u64)t * CD + lane * 4);
    float bestd = 1e30f; int bestc = 0x7fffffff;
    #pragma unroll
    for (int j = 0; j < 8; ++j) {
      const int col = __shfl(colv, j, 64);
      const float4 e = *(const float4*)(cb + (u64)col * CD + lane * 4);
      float p4 = x.x * e.x + x.y * e.y + x.z * e.z + x.w * e.w;
      #pragma unroll
      for (int off = 32; off >= 1; off >>= 1) p4 += __shfl_xor(p4, off, 64);
      const float d = e2[col] - 2.0f * p4;
      if (d < bestd || (d == bestd && col < bestc)) { bestd = d; bestc = col; }
    }
    const float4 q4 = *(const float4*)(cb + (u64)bestc * CD + lane * 4);
    float4 qd4;
    qd4.x = x.x + (q4.x - x.x);
    qd4.y = x.y + (q4.y - x.y);
    qd4.z = x.z + (q4.z - x.z);
    qd4.w = x.w + (q4.w - x.w);
    const u64 o = (u64)t * CD + lane * 4;
    *(float4*)(out1 + o) = q4;
    *(float4*)(out2 + o) = qd4;
  }
}

// ============ fallback path (exact fp32), used if ws too small ============

__global__ __launch_bounds__(256) void norms_kernel(const float* __restrict__ in,
                                                    const float* __restrict__ cb,
                                                    float* __restrict__ e2,
                                                    float* __restrict__ x2) {
  const int b = blockIdx.x;
  const int tid = threadIdx.x;
  if (b < 2048) {
    const int wave = tid >> 6, lane = tid & 63;
    const int row = b * 4 + wave;
    const float4 v = *(const float4*)(cb + row * CD + lane * 4);
    float s = v.x * v.x + v.y * v.y + v.z * v.z + v.w * v.w;
    #pragma unroll
    for (int off = 32; off >= 1; off >>= 1) s += __shfl_down(s, off, 64);
    if (lane == 0) e2[row] = s;
  } else {
    const int t = (b - 2048) * 256 + tid;
    const float* p = in + ((t >> 10) << 18) + (t & 1023);
    float s = 0.f;
    #pragma unroll 8
    for (int c = 0; c < CD; ++c) { const float v = p[c << 10]; s += v * v; }
    x2[t] = s;
  }
}

__global__ __launch_bounds__(256) void dist_argmin_kernel(
    const float* __restrict__ in, const float* __restrict__ cb,
    const float* __restrict__ e2, const float* __restrict__ x2,
    u64* __restrict__ packed) {
  __shared__ __align__(16) float As_[32][128];
  __shared__ __align__(16) float Bs_[32][128];
  const int tid = threadIdx.x;
  const int tx = tid & 15, ty = tid >> 4;
  const int tb = blockIdx.x & 255;
  const int ks = blockIdx.x >> 8;
  const int t0 = tb * 128;
  const int nbase = (t0 >> 10) << 18;
  const int tin = t0 & 1023;
  float xi[8];
  #pragma unroll
  for (int i = 0; i < 8; ++i)
    xi[i] = x2[t0 + ty * 4 + (i & 3) + ((i >> 2) << 6)];
  u64 best[8];
  #pragma unroll
  for (int i = 0; i < 8; ++i) best[i] = ~0ull;
  for (int kt = 0; kt < 32; ++kt) {
    const int k0 = ks * 4096 + kt * 128;
    float acc[8][8];
    #pragma unroll
    for (int i = 0; i < 8; ++i)
      #pragma unroll
      for (int j = 0; j < 8; ++j) acc[i][j] = 0.f;
    float ej[8];
    #pragma unroll
    for (int j = 0; j < 8; ++j)
      ej[j] = e2[k0 + tx * 4 + (j & 3) + ((j >> 2) << 6)];
    for (int ch = 0; ch < 8; ++ch) {
      const int c0 = ch * 32;
      #pragma unroll
      for (int p = 0; p < 4; ++p) {
        const int l = p * 1024 + tid * 4;
        const int cc = l >> 7, tt = l & 127;
        *(float4*)&As_[cc][tt] =
            *(const float4*)(in + nbase + (c0 + cc) * 1024 + tin + tt);
      }
      #pragma unroll
      for (int p = 0; p < 4; ++p) {
        const int ix = p * 256 + tid;
        const int kk = ix >> 3, cs = (ix & 7) * 4;
        const float4 v = *(const float4*)(cb + (k0 + kk) * CD + c0 + cs);
        Bs_[cs + 0][kk] = v.x; Bs_[cs + 1][kk] = v.y;
        Bs_[cs + 2][kk] = v.z; Bs_[cs + 3][kk] = v.w;
      }
      __syncthreads();
      #pragma unroll
      for (int cc = 0; cc < 32; ++cc) {
        const float4 a0 = *(const float4*)&As_[cc][ty * 4];
        const float4 a1 = *(const float4*)&As_[cc][64 + ty * 4];
        const float4 b0 = *(const float4*)&Bs_[cc][tx * 4];
        const float4 b1 = *(const float4*)&Bs_[cc][64 + tx * 4];
        const float a[8]  = {a0.x, a0.y, a0.z, a0.w, a1.x, a1.y, a1.z, a1.w};
        const float bb[8] = {b0.x, b0.y, b0.z, b0.w, b1.x, b1.y, b1.z, b1.w};
        #pragma unroll
        for (int i = 0; i < 8; ++i)
          #pragma unroll
          for (int j = 0; j < 8; ++j)
            acc[i][j] += a[i] * bb[j];
      }
      __syncthreads();
    }
    #pragma unroll
    for (int i = 0; i < 8; ++i) {
      u64 m = best[i];
      #pragma unroll
      for (int j = 0; j < 8; ++j) {
        const float dist = (xi[i] - 2.0f * acc[i][j]) + ej[j];
        const int kidx = k0 + tx * 4 + (j & 3) + ((j >> 2) << 6);
        const u64 pk = ((u64)__float_as_uint(dist) << 32) | (unsigned)kidx;
        m = pk < m ? pk : m;
      }
      best[i] = m;
    }
  }
  #pragma unroll
  for (int i = 0; i < 8; ++i) {
    u64 m = best[i];
    #pragma unroll
    for (int off = 8; off >= 1; off >>= 1) {
      const u64 o = shfl_xor_u64(m, off, 16);
      m = o < m ? o : m;
    }
    if (tx == 0)
      atomicMin(&packed[t0 + ty * 4 + (i & 3) + ((i >> 2) << 6)], m);
  }
}

__global__ __launch_bounds__(256) void output_kernel(
    const float* __restrict__ in, const float* __restrict__ cb,
    const u64* __restrict__ packed, float* __restrict__ out) {
  __shared__ float Ds[32][257];
  __shared__ int idxs[32];
  const int tid = threadIdx.x;
  const int t0 = blockIdx.x * 32;
  const int nbase = (t0 >> 10) << 18;
  const int tin = t0 & 1023;
  if (tid < 32) idxs[tid] = (int)(packed[t0 + tid] & 0xffffffffull);
  #pragma unroll 8
  for (int p = 0; p < 32; ++p) {
    const int lin = p * 256 + tid;
    const int cc = lin >> 5, tt = lin & 31;
    Ds[tt][cc] = in[nbase + cc * 1024 + tin + tt];
  }
  __syncthreads();
  float* out1 = out;
  float* out2 = out + 8388608;
  float* out3 = out + 16777216;
  for (int tt = 0; tt < 32; ++tt) {
    const float d = Ds[tt][tid];
    const int k = idxs[tt];
    const float q = cb[k * CD + tid];
    const float qd = d + (q - d);
    const int o = (t0 + tt) * CD + tid;
    out1[o] = q;
    out2[o] = qd;
    out3[o] = d;
  }
}

extern "C" void kernel_launch(void* const* d_in, const int* in_sizes, int n_in,
                              void* d_out, int out_size, void* d_ws, size_t ws_size,
                              hipStream_t stream) {
  const float* in = (const float*)d_in[0];
  const float* cb = (const float*)d_in[1];
  float* out = (float*)d_out;

  if (ws_size >= WS_NEED) {
    _Float16* Ap = (_Float16*)((char*)d_ws + WS_AP);
    _Float16* Bp = (_Float16*)((char*)d_ws + WS_BP);
    float* e2  = (float*)((char*)d_ws + WS_E2);
    float* e2b = (float*)((char*)d_ws + WS_E2B);
    u64* cand  = (u64*)((char*)d_ws + WS_CAND);
    float* out3 = out + 16777216;

    prep_kernel<<<1536, 256, 0, stream>>>(in, cb, Ap, Bp, e2, e2b, out3);
    screen_kernel<<<(T_TOT / MT) * SPLITS, 256, 0, stream>>>(Ap, Bp, e2b, cand);
    rescore_output_kernel<<<T_TOT / 32, 256, 0, stream>>>(cb, e2, cand, out);
  } else {
    u64* packed = (u64*)d_ws;
    float* e2 = (float*)((char*)d_ws + 262144);
    float* x2 = (float*)((char*)d_ws + 294912);
    (void)hipMemsetAsync(packed, 0xFF, T_TOT * sizeof(u64), stream);
    norms_kernel<<<2176, 256, 0, stream>>>(in, cb, e2, x2);
    dist_argmin_kernel<<<512, 256, 0, stream>>>(in, cb, e2, x2, packed);
    output_kernel<<<T_TOT / 32, 256, 0, stream>>>(in, cb, packed, out);
  }
}